// Round 4
// baseline (161.684 us; speedup 1.0000x reference)
//
#include <hip/hip_runtime.h>

#define H_IMG 1080
#define W_IMG 1920
#define HW_PIX (H_IMG * W_IMG)
#define GY 16
#define GX 16
#define GL 8
#define CF 12          // floats per grid cell
#define TPB 960        // 15 waves; one block = one image row, 2 px/thread

// One block per image row. y-lerp is row-uniform, so stage the whole y-lerped
// grid row G'[xc(16)][z(8)][c4(3)] (384 float4 = 6 KB) in LDS, then each
// thread processes 2 adjacent pixels: bilinear (x,z) interp from LDS, write
// 6 contiguous float4 (affine) + 6 floats (res) per thread, fully coalesced.
__global__ __launch_bounds__(TPB) void bg_kernel(
    const float* __restrict__ rgb,    // (3, H, W)
    const float* __restrict__ grids,  // (NUM, 16, 16, 8, 12)
    const int* __restrict__ idxp,
    float* __restrict__ out)          // [affine HW*12 | res HW*3]
{
    __shared__ float4 sg[GX * GL * 3];   // [xc][z][c4]

    const int tid = threadIdx.x;
    const int y = blockIdx.x;

    const float* grid = grids + (size_t)idxp[0] * (GY * GX * GL * CF);

    // row-uniform y interpolation
    float gyv = (float)y * (15.0f / 1079.0f);
    float fy = floorf(gyv);
    float wy = gyv - fy;
    int y0 = min(max((int)fy, 0), GY - 1);
    int y1 = min(y0 + 1, GY - 1);

    if (tid < GX * GL * 3) {
        int xc  = tid / 24;
        int rem = tid - xc * 24;
        int z   = rem / 3;
        int c4  = rem - z * 3;
        const float4* c0 = (const float4*)(grid + (size_t)((y0 * GX + xc) * GL + z) * CF) + c4;
        const float4* c1 = (const float4*)(grid + (size_t)((y1 * GX + xc) * GL + z) * CF) + c4;
        float4 a = *c0, b = *c1;
        float wy0 = 1.0f - wy;
        float4 rr;
        rr.x = wy0 * a.x + wy * b.x;
        rr.y = wy0 * a.y + wy * b.y;
        rr.z = wy0 * a.z + wy * b.z;
        rr.w = wy0 * a.w + wy * b.w;
        sg[tid] = rr;
    }
    __syncthreads();

    const int xp = 2 * tid;               // first of this thread's 2 pixels
    const int p = y * W_IMG + xp;

    float2 rv = *(const float2*)(rgb + p);
    float2 gv = *(const float2*)(rgb + HW_PIX + p);
    float2 bv = *(const float2*)(rgb + 2 * HW_PIX + p);

    float4 aff[2][3];
    float  res[2][3];

#pragma unroll
    for (int i = 0; i < 2; ++i) {
        float r = (i == 0) ? rv.x : rv.y;
        float g = (i == 0) ? gv.x : gv.y;
        float b = (i == 0) ? bv.x : bv.y;

        float gray = 0.299f * r + 0.587f * g + 0.114f * b;

        float gxv = (float)(xp + i) * (15.0f / 1919.0f);
        float fx = floorf(gxv), wx = gxv - fx;
        float gz = fminf(fmaxf(gray, 0.0f), 1.0f) * 7.0f;
        float fz = floorf(gz), wz = gz - fz;

        int x0g = min(max((int)fx, 0), GX - 1);
        int x1g = min(x0g + 1, GX - 1);
        int z0 = min(max((int)fz, 0), GL - 1);
        int z1 = min(z0 + 1, GL - 1);

        float w00 = (1.0f - wx) * (1.0f - wz);
        float w01 = (1.0f - wx) * wz;
        float w10 = wx * (1.0f - wz);
        float w11 = wx * wz;

        const float4* A = sg + (x0g * GL + z0) * 3;
        const float4* B = sg + (x0g * GL + z1) * 3;
        const float4* C = sg + (x1g * GL + z0) * 3;
        const float4* D = sg + (x1g * GL + z1) * 3;

#pragma unroll
        for (int j = 0; j < 3; ++j) {
            float4 va = A[j], vb = B[j], vc = C[j], vd = D[j];
            float4 o;
            o.x = fmaf(w00, va.x, fmaf(w01, vb.x, fmaf(w10, vc.x, w11 * vd.x)));
            o.y = fmaf(w00, va.y, fmaf(w01, vb.y, fmaf(w10, vc.y, w11 * vd.y)));
            o.z = fmaf(w00, va.z, fmaf(w01, vb.z, fmaf(w10, vc.z, w11 * vd.z)));
            o.w = fmaf(w00, va.w, fmaf(w01, vb.w, fmaf(w10, vc.w, w11 * vd.w)));
            aff[i][j] = o;
        }
        res[i][0] = fmaf(aff[i][0].x, r, fmaf(aff[i][0].y, g, fmaf(aff[i][0].z, b, aff[i][0].w)));
        res[i][1] = fmaf(aff[i][1].x, r, fmaf(aff[i][1].y, g, fmaf(aff[i][1].z, b, aff[i][1].w)));
        res[i][2] = fmaf(aff[i][2].x, r, fmaf(aff[i][2].y, g, fmaf(aff[i][2].z, b, aff[i][2].w)));
    }

    // affine: float4 index p*3 .. p*3+5 — 96B contiguous per thread, coalesced
    float4* ao = (float4*)out + (size_t)p * 3;
    ao[0] = aff[0][0]; ao[1] = aff[0][1]; ao[2] = aff[0][2];
    ao[3] = aff[1][0]; ao[4] = aff[1][1]; ao[5] = aff[1][2];

    // res: 6 floats at HW*12 + p*3, 24B contiguous per thread
    float* ro = out + (size_t)HW_PIX * 12 + (size_t)p * 3;
    ro[0] = res[0][0]; ro[1] = res[0][1]; ro[2] = res[0][2];
    ro[3] = res[1][0]; ro[4] = res[1][1]; ro[5] = res[1][2];
}

extern "C" void kernel_launch(void* const* d_in, const int* in_sizes, int n_in,
                              void* d_out, int out_size, void* d_ws, size_t ws_size,
                              hipStream_t stream) {
    const float* rgb   = (const float*)d_in[0];
    const float* grids = (const float*)d_in[1];
    const int*   idx   = (const int*)d_in[2];
    float*       out   = (float*)d_out;

    dim3 grid(H_IMG);     // one block per row
    dim3 block(TPB);      // 960 threads = 15 waves
    bg_kernel<<<grid, block, 0, stream>>>(rgb, grids, idx, out);
}